// Round 2
// baseline (169.931 us; speedup 1.0000x reference)
//
#include <hip/hip_runtime.h>
#include <math.h>

// out [1, 128, N] f32:
//   rows   0.. 63 : pdf^T               (pdf [N,64] row-major)
//   rows  64.. 95 : te[c] broadcast     (timestep embedding, single vector)
//   rows  96..127 : mask[p] ? me1[c] : me0[c]
//
// ws layout: te[0..31], me0[32..63], me1[64..95]

#define HALF 32
#define TS 256  // points per tile

// LDS transpose tile, channel-major: row stride 256 floats, +4 floats pad
// every 8 rows. Writes: bank = (4*(q>>1) + const + d) mod 32 -> 2-way (free).
// Reads: contiguous 16B-aligned ds_read_b128 -> conflict-free.
__device__ __forceinline__ int ldsIdx(int c, int p) {
    return c * 256 + ((c >> 3) << 2) + p;
}
#define TILE_FLOATS 16412  // ldsIdx(63,255)+1

__global__ void embed_small_kernel(const float* __restrict__ t,
                                   const float* __restrict__ ef_w1, const float* __restrict__ ef_b1,
                                   const float* __restrict__ ef_w2, const float* __restrict__ ef_b2,
                                   const float* __restrict__ em_w1, const float* __restrict__ em_b1,
                                   const float* __restrict__ em_w2, const float* __restrict__ em_b2,
                                   float* __restrict__ ws) {
    __shared__ float h[3][64];
    const int tid = threadIdx.x;
    const float log_scale = 0.2970934777f;  // ln(10000)/31

    if (tid < 192) {
        const int v = tid >> 6;      // 0: sin-emb(t)->ef, 1: sin-emb(0)->em, 2: sin-emb(1)->em
        const int j = tid & 63;
        const float val = (v == 0) ? t[0] : (float)(v - 1);
        const float* w1 = (v == 0) ? ef_w1 : em_w1;
        const float* b1 = (v == 0) ? ef_b1 : em_b1;
        float acc = b1[j];
        for (int k = 0; k < HALF; ++k) {
            float f = expf(-(float)k * log_scale);
            float ang = val * f;
            float s, c;
            sincosf(ang, &s, &c);
            acc += s * w1[j * 64 + k] + c * w1[j * 64 + HALF + k];
        }
        h[v][j] = (acc > 0.0f) ? acc : 0.1f * acc;  // LeakyReLU(0.1)
    }
    __syncthreads();
    if (tid < 96) {
        const int v = tid >> 5;
        const int c = tid & 31;
        const float* w2 = (v == 0) ? ef_w2 : em_w2;
        const float* b2 = (v == 0) ? ef_b2 : em_b2;
        float acc = b2[c];
        for (int j = 0; j < 64; ++j) acc += h[v][j] * w2[c * 64 + j];
        ws[v * 32 + c] = acc;
    }
}

__global__ __launch_bounds__(256) void pvcnn_cond_kernel(
        const float* __restrict__ pdf,
        const int* __restrict__ mask,
        const float* __restrict__ ws,
        float* __restrict__ out,
        int N) {
    __shared__ float tile[TILE_FLOATS];
    __shared__ float emb[96];

    const int tid = threadIdx.x;
    const long long p0 = (long long)blockIdx.x * TS;
    const bool fast = (p0 + TS <= (long long)N) && ((N & 3) == 0);

    if (tid < 96) emb[tid] = ws[tid];

    // ---- phase 1: pdf tile -> LDS (channel-major) ----
    if (fast) {
        const float4* src = (const float4*)(pdf + p0 * 64);
        #pragma unroll
        for (int it = 0; it < 16; ++it) {
            const int f = tid + it * 256;   // chunk index: 256 pts x 16 chunks
            const int p = f >> 4;
            const int c0 = (f & 15) * 4;
            const float4 v = src[f];
            const int b = ldsIdx(c0, p);    // rows c0..c0+3 share the pad term
            tile[b + 0 * 256] = v.x;
            tile[b + 1 * 256] = v.y;
            tile[b + 2 * 256] = v.z;
            tile[b + 3 * 256] = v.w;
        }
    } else {
        #pragma unroll
        for (int it = 0; it < 16; ++it) {
            const int f = tid + it * 256;
            const int p = f >> 4;
            const int c0 = (f & 15) * 4;
            float4 v = make_float4(0.f, 0.f, 0.f, 0.f);
            if (p0 + p < (long long)N)
                v = ((const float4*)(pdf + (p0 + p) * 64))[f & 15];
            const int b = ldsIdx(c0, p);
            tile[b + 0 * 256] = v.x;
            tile[b + 1 * 256] = v.y;
            tile[b + 2 * 256] = v.z;
            tile[b + 3 * 256] = v.w;
        }
    }

    const int l = tid & 63;        // lane
    const int w = tid >> 6;        // wave 0..3
    const long long col = p0 + 4 * l;

    int4 m4 = make_int4(0, 0, 0, 0);
    if (fast) {
        m4 = ((const int4*)mask)[(p0 >> 2) + l];
    } else {
        if (col + 0 < N) m4.x = mask[col + 0];
        if (col + 1 < N) m4.y = mask[col + 1];
        if (col + 2 < N) m4.z = mask[col + 2];
        if (col + 3 < N) m4.w = mask[col + 3];
    }

    __syncthreads();

    // ---- phase 2: 128 rows, interleaved r = 4s + w; float4 stores (1KB/wave) ----
    if (fast) {
        float* op = out + (long long)w * N + col;   // row w, this thread's columns
        const long long stride = 4LL * N;           // 4 rows per iteration
        #pragma unroll
        for (int s = 0; s < 32; ++s) {
            const int r = 4 * s + w;
            float4 v;
            if (s < 16) {                 // r in [0,64): transpose rows
                v = *(const float4*)&tile[ldsIdx(r, 4 * l)];
            } else if (s < 24) {          // r in [64,96): te broadcast
                const float e = emb[r - 64];
                v = make_float4(e, e, e, e);
            } else {                      // r in [96,128): mask embedding
                const int c = r - 96;
                const float e0 = emb[32 + c];
                const float e1 = emb[64 + c];
                v = make_float4(m4.x ? e1 : e0, m4.y ? e1 : e0,
                                m4.z ? e1 : e0, m4.w ? e1 : e0);
            }
            *(float4*)(op + (long long)s * stride) = v;
        }
    } else {
        for (int s = 0; s < 32; ++s) {
            const int r = 4 * s + w;
            float vals[4];
            if (s < 16) {
                #pragma unroll
                for (int j = 0; j < 4; ++j) vals[j] = tile[ldsIdx(r, 4 * l + j)];
            } else if (s < 24) {
                const float e = emb[r - 64];
                vals[0] = vals[1] = vals[2] = vals[3] = e;
            } else {
                const int c = r - 96;
                const float e0 = emb[32 + c];
                const float e1 = emb[64 + c];
                vals[0] = m4.x ? e1 : e0;
                vals[1] = m4.y ? e1 : e0;
                vals[2] = m4.z ? e1 : e0;
                vals[3] = m4.w ? e1 : e0;
            }
            #pragma unroll
            for (int j = 0; j < 4; ++j)
                if (col + j < (long long)N)
                    out[(long long)r * N + col + j] = vals[j];
        }
    }
}

extern "C" void kernel_launch(void* const* d_in, const int* in_sizes, int n_in,
                              void* d_out, int out_size, void* d_ws, size_t ws_size,
                              hipStream_t stream) {
    // 0: inputs [1,6,N]; 1: t [1]; 2: mask [N] i32; 3: pdf [N,64];
    // 4..7: ef_w1,ef_b1,ef_w2,ef_b2; 8..11: em_w1,em_b1,em_w2,em_b2
    const float* t     = (const float*)d_in[1];
    const int*   mask  = (const int*)d_in[2];
    const float* pdf   = (const float*)d_in[3];
    const float* ef_w1 = (const float*)d_in[4];
    const float* ef_b1 = (const float*)d_in[5];
    const float* ef_w2 = (const float*)d_in[6];
    const float* ef_b2 = (const float*)d_in[7];
    const float* em_w1 = (const float*)d_in[8];
    const float* em_b1 = (const float*)d_in[9];
    const float* em_w2 = (const float*)d_in[10];
    const float* em_b2 = (const float*)d_in[11];

    float* out = (float*)d_out;
    float* ws  = (float*)d_ws;
    const int N = in_sizes[2];

    embed_small_kernel<<<1, 192, 0, stream>>>(t, ef_w1, ef_b1, ef_w2, ef_b2,
                                              em_w1, em_b1, em_w2, em_b2, ws);

    const int nblocks = (N + TS - 1) / TS;
    pvcnn_cond_kernel<<<nblocks, 256, 0, stream>>>(pdf, mask, ws, out, N);
}